// Round 5
// baseline (370.875 us; speedup 1.0000x reference)
//
#include <hip/hip_runtime.h>
#include <hip/hip_bf16.h>
#include <stdint.h>

typedef short short8 __attribute__((ext_vector_type(8)));
typedef float f32x4 __attribute__((ext_vector_type(4)));

__device__ __forceinline__ short f2bf(float f) {
    __hip_bfloat16 h = __float2bfloat16(f);
    return __builtin_bit_cast(short, h);
}

// ---- prep 0: xm(b,h,w,ci) = bf16( x * style )  — removes ALL modulate work
// from the conv hot loop and enables pure-DMA A staging.
__global__ void prep_xm(const float* __restrict__ x,
                        const float* __restrict__ style,
                        __hip_bfloat16* __restrict__ xm)
{
    const size_t gi = ((size_t)blockIdx.x * 256 + threadIdx.x) * 8;
    const int b  = (int)(gi >> 22);            // 128*128*256 = 2^22
    const int ci = (int)(gi & 255);
    float4 x0 = *(const float4*)(x + gi);
    float4 x1 = *(const float4*)(x + gi + 4);
    float4 s0 = *(const float4*)(style + b * 256 + ci);
    float4 s1 = *(const float4*)(style + b * 256 + ci + 4);
    short8 m;
#pragma unroll
    for (int jj = 0; jj < 4; ++jj) {
        m[jj]     = f2bf((&x0.x)[jj] * (&s0.x)[jj]);
        m[jj + 4] = f2bf((&x1.x)[jj] * (&s1.x)[jj]);
    }
    *(short8*)(xm + gi) = m;
}

// ---- prep 1a: K2(ci,co) = sum_p kernel[p,ci,co]^2  (256 blocks) ------------
__global__ void prep_k2(const float* __restrict__ kern, float* __restrict__ K2)
{
    const int ci = blockIdx.x, co = threadIdx.x;
    float acc = 0.f;
#pragma unroll
    for (int p = 0; p < 9; ++p) {
        float w = kern[(p * 256 + ci) * 256 + co];
        acc += w * w;
    }
    K2[ci * 256 + co] = acc;
}

// ---- prep 1b: demod(b,co) = 1/sqrt( sum_ci style^2 * K2 + eps ) ------------
__global__ void prep_demod(const float* __restrict__ style,
                           const float* __restrict__ K2,
                           float* __restrict__ demod)
{
    const int b = blockIdx.x, co = threadIdx.x;
    __shared__ float s2[256];
    float s = style[b * 256 + co];
    s2[co] = s * s;
    __syncthreads();
    float acc = 0.f;
#pragma unroll 8
    for (int ci = 0; ci < 256; ++ci)
        acc += s2[ci] * K2[ci * 256 + co];
    demod[b * 256 + co] = 1.0f / sqrtf(acc + 1e-7f);
}

// ---- prep 2: fragment-major bf16 weights (unchanged, verified in v5) -------
__global__ void prep_kf(const float* __restrict__ kern,
                        __hip_bfloat16* __restrict__ kf)
{
    const int st = blockIdx.x;                 // 0..71
    const int sl = st / 3, tp = st - sl * 3;
    const int dh = sl >> 3, cc = sl & 7;
    const int p  = dh * 3 + tp;
    const int t    = threadIdx.x;
    const int lane = t & 63, jt2 = t >> 6;
    const int l15  = lane & 15, lk = lane >> 4;
    const int cib  = cc * 32 + lk * 8;
#pragma unroll
    for (int jj = 0; jj < 4; ++jj) {
        const int jt = jj * 4 + jt2;
        const int co = jt * 16 + l15;
        short8 v;
#pragma unroll
        for (int e = 0; e < 8; ++e)
            v[e] = f2bf(kern[(size_t)(p * 256 + cib + e) * 256 + co]);
        *(short8*)(kf + ((size_t)(st * 16 + jt) * 64 + lane) * 8) = v;
    }
}

// ---- main: implicit-GEMM conv, pure-DMA staging, bf16 MFMA core ------------
// v6 vs v5 (post-mortem: 5 variants pinned at 195-210us; the invariants are
// the in-loop x modulate/staging path and its 1.25e7 LDS conflicts — the
// 2-phase "stage+barrier" overhead the guide documents as ~70% of such loops):
//  * x pre-modulated to bf16 by prep_xm -> conv stages A AND B purely via
//    global_load_lds width=16. Hot loop has NO staging VALU, NO staging
//    registers, NO ds_writes, no lgkm dep before the barrier (m97 template).
//  * Xs layout linear [130][32] (DMA-compatible). Bank conflicts fixed by a
//    chunk-XOR swizzle via PRE-SWIZZLED GLOBAL SRC (both-sides involution,
//    rule #21): 16B chunk c of row r sits in slot c ^ ((r>>1)&3); the
//    A-fragment ds_read applies the same XOR. Net: 2 lanes/bank-group (free).
//  * Ss gone; LDS 66.3 KB -> 2 blocks/CU (same residency as v5, far less
//    per-slice serial work).
__global__ __launch_bounds__(256) void conv_mfma(
    const __hip_bfloat16* __restrict__ xm,
    const __hip_bfloat16* __restrict__ kf,
    const float* __restrict__ demod,
    float* __restrict__ out)
{
    __shared__ __align__(16) __hip_bfloat16 Xs[2][130 * 32];    // 16.6 KB
    __shared__ __align__(16) __hip_bfloat16 KfB[2][24 * 512];   // 48 KB
    __shared__ float Ds[128];

    const int t    = threadIdx.x;
    const int bid  = blockIdx.x;
    const int L    = ((bid & 7) << 8) | (bid >> 3);   // XCD-contiguous work id
    const int n0   = (L & 1) << 7;                    // cout tile: 0 or 128
    const int bh   = L >> 1;                          // 0..1023
    const int b    = bh >> 7, h = bh & 127;
    const int wave = t >> 6, lane = t & 63;
    const int wr   = (wave >> 1) << 6;          // wave row base
    const int wc   = (wave & 1) << 6;           // wave col base
    const int wjl  = (wave & 1) << 2;           // local j-tile base in KfB
    const int l15  = lane & 15, lk = lane >> 4;
    const int jb0  = (L & 1) << 3;              // global j-tile base (n0 half)

    if (t < 128) Ds[t] = demod[b * 256 + n0 + t];
    if (t < 32) {                               // w-halo rows, never re-written
        const __hip_bfloat16 z = __float2bfloat16(0.f);
        Xs[0][t] = z; Xs[0][129 * 32 + t] = z;
        Xs[1][t] = z; Xs[1][129 * 32 + t] = z;
    }

    f32x4 acc[4][4] = {};

    const int slo = (h == 0)   ? 8  : 0;        // valid slices are contiguous
    const int shi = (h == 127) ? 16 : 24;

    // A staging: 8 wave-DMAs cover rows 1..128 (16 rows each). Dest linear;
    // global src pre-swizzled so slot (lane&3) of row r holds chunk
    // (lane&3) ^ ((r>>1)&3).
    auto stage_A = [&](int s, int buf) {
        const int h2  = h + (s >> 3) - 1;
        const int ci0 = (s & 7) << 5;
        const size_t rowbase = (size_t)(b * 128 + h2) * 128;
        const int lr = lane >> 2, slot = lane & 3;
#pragma unroll
        for (int k = 0; k < 2; ++k) {
            const int d = (wave << 1) | k;
            const int r = 1 + (d << 4) + lr;            // Xs row this lane fills
            const int c = slot ^ ((r >> 1) & 3);        // logical ci chunk
            const __hip_bfloat16* src =
                xm + (rowbase + (r - 1)) * 256 + ci0 + (c << 3);
            __builtin_amdgcn_global_load_lds(
                (const __attribute__((address_space(1))) void*)src,
                (__attribute__((address_space(3))) void*)&Xs[buf][(1 + (d << 4)) * 32],
                16, 0, 0);
        }
    };
    // B staging: 24 x 1KB fragment chunks (verified layout from v5).
    auto stage_B = [&](int s, int buf) {
#pragma unroll
        for (int k = 0; k < 6; ++k) {
            const int c = (k << 2) + wave;      // 0..23 = tp*8 + jl
            const __hip_bfloat16* src =
                kf + ((size_t)(s * 48 + ((c >> 3) << 4) + jb0 + (c & 7)) * 64
                      + lane) * 8;
            __builtin_amdgcn_global_load_lds(
                (const __attribute__((address_space(1))) void*)src,
                (__attribute__((address_space(3))) void*)&KfB[buf][c * 512],
                16, 0, 0);
        }
    };

    // ---- prologue: stage slice slo into buffer 0 ----
    stage_A(slo, 0);
    stage_B(slo, 0);
    __syncthreads();                            // drains DMA; publishes buf0

    int cur = 0;
    for (int s = slo; s < shi; ++s, cur ^= 1) {
        if (s + 1 < shi) {                      // stage next slice first:
            stage_A(s + 1, cur ^ 1);            // max issue->drain distance
            stage_B(s + 1, cur ^ 1);
        }

        // ---- compute current slice: 3 taps x 4x4 tiles ----
#pragma unroll
        for (int tp = 0; tp < 3; ++tp) {        // dw=tp-1; pixel m reads row m+tp
            short8 af[4], bfr[4];
#pragma unroll
            for (int j = 0; j < 4; ++j)         // wave-contiguous 1 KB ds_read
                bfr[j] = *(const short8*)&KfB[cur][((tp << 3) + wjl + j) * 512
                                                   + lane * 8];
#pragma unroll
            for (int i = 0; i < 4; ++i) {
                const int R = wr + i * 16 + l15 + tp;
                af[i] = *(const short8*)&Xs[cur][R * 32
                                                 + ((lk ^ ((R >> 1) & 3)) << 3)];
            }
#pragma unroll
            for (int i = 0; i < 4; ++i)
#pragma unroll
                for (int j = 0; j < 4; ++j)
                    acc[i][j] = __builtin_amdgcn_mfma_f32_16x16x32_bf16(
                        af[i], bfr[j], acc[i][j], 0, 0, 0);
        }
        __syncthreads();        // drains next-slice DMA; publishes buffers
    }

    // ---- epilogue: demod scale + f32 store (C/D: col=lane&15, row=(lane>>4)*4+r)
    float dj[4];
#pragma unroll
    for (int j = 0; j < 4; ++j) dj[j] = Ds[wc + j * 16 + l15];
    const size_t obase = (size_t)(b * 128 + h) * 128 * 256 + n0;
#pragma unroll
    for (int i = 0; i < 4; ++i) {
#pragma unroll
        for (int j = 0; j < 4; ++j) {
            const int n = wc + j * 16 + l15;
#pragma unroll
            for (int r = 0; r < 4; ++r) {
                const int m = wr + i * 16 + (lane >> 4) * 4 + r;
                out[obase + (size_t)m * 256 + n] = acc[i][j][r] * dj[j];
            }
        }
    }
}

extern "C" void kernel_launch(void* const* d_in, const int* in_sizes, int n_in,
                              void* d_out, int out_size, void* d_ws, size_t ws_size,
                              hipStream_t stream)
{
    const float* x     = (const float*)d_in[0];
    const float* style = (const float*)d_in[1];
    const float* kern  = (const float*)d_in[2];
    float* out = (float*)d_out;

    char* ws = (char*)d_ws;
    __hip_bfloat16* xm = (__hip_bfloat16*)ws;            // 33.55M bf16 (67.1 MB)
    float* demod = (float*)(ws + 67108864);              // 2048 f32   (8 KB)
    float* K2    = (float*)(ws + 67108864 + 8192);       // 65536 f32  (256 KB)
    __hip_bfloat16* kT = (__hip_bfloat16*)(ws + 67108864 + 270336); // 1.18 MB

    prep_xm   <<<16384, 256, 0, stream>>>(x, style, xm);
    prep_k2   <<<256,   256, 0, stream>>>(kern, K2);
    prep_demod<<<8,     256, 0, stream>>>(style, K2, demod);
    prep_kf   <<<72,    256, 0, stream>>>(kern, kT);
    conv_mfma <<<2048,  256, 0, stream>>>(xm, kT, demod, out);
}